// Round 4
// baseline (613.656 us; speedup 1.0000x reference)
//
#include <hip/hip_runtime.h>

// EncConvNet fused v6: conv7x7s3+sq -> fc1+sq -> fc2, one kernel.
// v5 -> v6: OCCUPANCY 2x via per-chunk fc1/fc2. v5 was latency-bound
// (VALU 33%, LDS-pipe ~47%, 1 block/CU, 16 waves lockstep on barriers).
// Key change: fc1+fc2 run per 16-image conv chunk, so hb shrinks from
// [64k4][64img] (66.5KB) to [64k4][16img] (17.4KB) and h2 disappears
// (fc2 = per-lane ds_add_f32 scatter into a 640-float accumulator).
// LDS total 70.1KB -> 2 blocks/CU -> 32 waves/CU = 8 waves/SIMD, and the
// two resident blocks overlap conv/fc phases across barriers.
//  - conv: identical to v5 (c wave-uniform -> SGPR taps, 64 VGPR, no spill).
//  - fc1 reshape: lane = o_sub*16+img16, one (output,image) pair per lane,
//    full k=0..255 sum in-register (same ascending order as v5). Weights via
//    vector loads (4 distinct rows/wave -> L1 broadcast) on the idle VMEM
//    pipe; bias from fc1_b[o] per lane.
//  - fc2: ob[] pre-seeded with fc2_b, then each lane atomicAdd's
//    h2*fc2_w[j][o] for j=0..9 (ds_add_f32, ~640 instrs/block).
//  - hb pitch 17 float4: write banks (2y+xh+g)&7 uniform; read 16 distinct
//    addrs x 4-lane broadcast. Conflict-clean both sides.

#define BLK_IMGS    64
#define CHUNK_IMGS  16
#define NCHUNK      4
#define XCH_FLOATS  (CHUNK_IMGS * 784)   // 12544 floats per chunk
#define HB_PITCH    17                   // float4 pitch (16 imgs + 1 pad)

// LDS float offsets
#define LDS_XBUF    0                    // 12544 (single buffer)
#define LDS_H       12544                // 64*17*4 = 4352 floats
#define LDS_OUT     16896                // 640 floats (64 img x 10 outs)
#define LDS_TOTAL_F 17536                // -> 70144 bytes -> 2 blocks/CU

__global__ __launch_bounds__(1024)
void encconv_fused6(const float* __restrict__ x,
                    const float* __restrict__ conv_w,
                    const float* __restrict__ conv_b,
                    const float* __restrict__ fc1_w,
                    const float* __restrict__ fc1_b,
                    const float* __restrict__ fc2_w,
                    const float* __restrict__ fc2_b,
                    float* __restrict__ out)
{
    extern __shared__ float lds[];
    float*  xbuf = lds + LDS_XBUF;
    float4* hb   = (float4*)(lds + LDS_H);
    float*  ob   = lds + LDS_OUT;

    const int tid  = threadIdx.x;
    const int blk  = blockIdx.x;
    const long base_img = (long)blk * BLK_IMGS;

    // ---- conv-phase roles: wave = c*4 + ghi (c uniform per wave) ----
    //      lane = glo*16 + y*2 + xh ; image g = ghi*4 + glo (0..15)
    const int lane = tid & 63;
    const int c    = __builtin_amdgcn_readfirstlane((tid >> 6) & 3);
    const int ghi  = __builtin_amdgcn_readfirstlane(tid >> 8);       // 0..3
    const int glo  = lane >> 4;      // 0..3
    const int y    = (lane >> 1) & 7;
    const int xh   = lane & 1;
    const int g    = ghi * 4 + glo;  // image-in-chunk 0..15

    // conv taps: wave-uniform address -> s_load -> SGPRs (zero VGPR cost)
    float ws[49];
    #pragma unroll
    for (int i = 0; i < 49; ++i) ws[i] = conv_w[c * 49 + i];
    const float cb = conv_b[c];

    // ---- fc1-phase roles: lane = o_sub*16 + img16; output o = wave*4+o_sub
    const int o_sub = (tid >> 4) & 3;
    const int img16 = tid & 15;
    const int o     = ((tid >> 6) << 2) + o_sub;   // 0..63

    // seed ob with fc2 bias (adds then accumulate on top)
    if (tid < 640) ob[tid] = fc2_b[tid % 10];

    const float* xblk = x + base_img * 784;

    // ---- prefetch chunk 0 into registers (coalesced: 3136 float4) ----
    float4 pf0, pf1, pf2, pf3;
    {
        const float* src = xblk;
        pf0 = *(const float4*)(src + 4 * tid);
        pf1 = *(const float4*)(src + 4 * (tid + 1024));
        pf2 = *(const float4*)(src + 4 * (tid + 2048));
        if (tid < 64) pf3 = *(const float4*)(src + 4 * (tid + 3072));
    }

    // fc1 + fc2 for a completed chunk (hb holds that chunk's h, k-major)
    auto fc1fc2 = [&](int ch) {
        const float* wrow = fc1_w + o * 256;   // 4 distinct rows per wave
        float acc = 0.f;
        #pragma unroll 4
        for (int k4 = 0; k4 < 64; ++k4) {
            float4 h4 = hb[k4 * HB_PITCH + img16];          // 16 addrs, bcast
            float4 w4 = *(const float4*)(wrow + k4 * 4);    // VMEM, L1
            acc = fmaf(h4.x, w4.x, acc); acc = fmaf(h4.y, w4.y, acc);
            acc = fmaf(h4.z, w4.z, acc); acc = fmaf(h4.w, w4.w, acc);
        }
        float t  = acc + fc1_b[o];
        float h2 = t * t;
        const int ig = ch * CHUNK_IMGS + img16;             // global image 0..63
        #pragma unroll
        for (int j = 0; j < 10; ++j) {
            atomicAdd(ob + ig * 10 + j, h2 * fc2_w[j * 64 + o]);
        }
    };

    // ---- main loop: conv chunk ch; fc1/fc2 of chunk ch-1 overlaps commit ----
    for (int ch = 0; ch < NCHUNK; ++ch) {
        // commit prefetched regs to LDS (lane-contiguous ds_write_b128)
        *(float4*)(xbuf + 4 * tid)          = pf0;
        *(float4*)(xbuf + 4 * (tid + 1024)) = pf1;
        *(float4*)(xbuf + 4 * (tid + 2048)) = pf2;
        if (tid < 64) *(float4*)(xbuf + 4 * (tid + 3072)) = pf3;

        // fc1+fc2 of the previous chunk (reads hb; xbuf commit is disjoint)
        if (ch > 0) fc1fc2(ch - 1);
        __syncthreads();   // B1: xbuf ready; prev-chunk fc1 done (hb free)

        // issue next chunk's prefetch; conv compute below hides its latency
        if (ch + 1 < NCHUNK) {
            const float* src = xblk + (ch + 1) * XCH_FLOATS;
            pf0 = *(const float4*)(src + 4 * tid);
            pf1 = *(const float4*)(src + 4 * (tid + 1024));
            pf2 = *(const float4*)(src + 4 * (tid + 2048));
            if (tid < 64) pf3 = *(const float4*)(src + 4 * (tid + 3072));
        }

        // conv: image g, row y, channel c (uniform), outputs 4xh..4xh+3
        float acc0 = 0.f, acc1 = 0.f, acc2 = 0.f, acc3 = 0.f;
        const float* xi = xbuf + g * 784;
        #pragma unroll
        for (int rr = 0; rr < 7; ++rr) {
            const float* rp = xi + (3 * y + rr) * 28 + 12 * xh;  // 16B aligned
            float4 r0 = *(const float4*)(rp + 0);
            float4 r1 = *(const float4*)(rp + 4);
            float4 r2 = *(const float4*)(rp + 8);
            float4 r3 = *(const float4*)(rp + 12);
            float r[16] = { r0.x, r0.y, r0.z, r0.w,
                            r1.x, r1.y, r1.z, r1.w,
                            r2.x, r2.y, r2.z, r2.w,
                            r3.x, r3.y, r3.z, r3.w };
            #pragma unroll
            for (int kx = 0; kx < 7; ++kx) {
                const float w = ws[rr * 7 + kx];     // SGPR operand
                acc0 = fmaf(r[0 + kx], w, acc0);
                acc1 = fmaf(r[3 + kx], w, acc1);
                acc2 = fmaf(r[6 + kx], w, acc2);
                acc3 = fmaf(r[9 + kx], w, acc3);
            }
        }

        // bias + square -> hb (per-chunk, k-major: k4 = c*16 + y*2 + xh)
        float4 hv;
        hv.x = acc0 + cb; hv.x *= hv.x;
        hv.y = acc1 + cb; hv.y *= hv.y;
        hv.z = acc2 + cb; hv.z *= hv.z;
        hv.w = acc3 + cb; hv.w *= hv.w;
        hb[(c * 16 + y * 2 + xh) * HB_PITCH + g] = hv;

        __syncthreads();   // B2: hb ready; xbuf consumed (next commit safe)
    }

    // fc1+fc2 for the last chunk
    fc1fc2(NCHUNK - 1);
    __syncthreads();

    // ---- coalesced output store: 640 floats per block ----
    if (tid < 160) {
        float4 v = *(const float4*)(ob + tid * 4);
        *(float4*)(out + (long)blk * 640 + tid * 4) = v;
    }
}

extern "C" void kernel_launch(void* const* d_in, const int* in_sizes, int n_in,
                              void* d_out, int out_size, void* d_ws, size_t ws_size,
                              hipStream_t stream) {
    const float* x      = (const float*)d_in[0];
    const float* conv_w = (const float*)d_in[1];
    const float* conv_b = (const float*)d_in[2];
    const float* fc1_w  = (const float*)d_in[3];
    const float* fc1_b  = (const float*)d_in[4];
    const float* fc2_w  = (const float*)d_in[5];
    const float* fc2_b  = (const float*)d_in[6];
    float* out = (float*)d_out;

    const int B = in_sizes[0] / 784;
    const int blocks = (B + BLK_IMGS - 1) / BLK_IMGS;   // 1024 for B=65536
    const size_t lds_bytes = LDS_TOTAL_F * sizeof(float);  // 70144

    // >64KB dynamic LDS needs the attribute raised (idempotent).
    static bool attr_set = false;
    if (!attr_set) {
        (void)hipFuncSetAttribute((const void*)encconv_fused6,
                                  hipFuncAttributeMaxDynamicSharedMemorySize,
                                  (int)lds_bytes);
        attr_set = true;
    }

    encconv_fused6<<<blocks, 1024, lds_bytes, stream>>>(
        x, conv_w, conv_b, fc1_w, fc1_b, fc2_w, fc2_b, out);
}

// Round 5
// 446.299 us; speedup vs baseline: 1.3750x; 1.3750x over previous
//
#include <hip/hip_runtime.h>

// EncConvNet fused v7: conv7x7s3+sq -> fc1+sq -> fc2, one kernel.
// v6 FAILED (423us): per-chunk fc1 lost s_load weights, fc2 LDS atomics
// serialized, 2nd block never helped. v7 reverts to v5's fc1 and instead
// removes xbuf ENTIRELY: conv reads x straight from global (input is
// L2/L3-resident: FETCH 105MB < 205MB input). This frees 50KB LDS ->
// LDS = hb[64][64] + h2b[16][64] = 81920B exactly -> 2 blocks/CU,
// 32 waves/CU = 8/SIMD, and the conv's VMEM phase anti-phases against the
// other block's LDS-heavy fc1 (pipe mixing).
//  - conv roles: wave = (c, imgHi) both uniform -> 49 taps in SGPRs (no
//    spill at 64-VGPR budget). Thread = (imgLo, yh, xh) computes a 4-row x
//    4-col output tile: 16 rows x 4 aligned float4 global loads, 784 FMA
//    -> 3.06 FMA/word (v5: 1.75), and conv needs NO barriers.
//  - FMA order per output identical to v5 (rr asc, kx asc) -> bit-identical.
//  - fc1: v5 verbatim (wave w -> outputs 4w..4w+3, s_load weights, lanes =
//    64 images, contiguous conflict-free hb reads), pitch 64 (unpadded).
//  - fc2: wave j (0..9) -> output j, weights+bias via uniform s_load,
//    h2b reads contiguous, direct scattered global store (640 floats).
//  - Barriers per block: 9 (v5) -> 2.

#define BLK_IMGS  64
#define LDS_H2    16384                  // float offset of h2b
#define LDS_TOTAL_F 20480                // 16384 + 4096 -> 81920 bytes

__global__ __launch_bounds__(1024)
void encconv_fused7(const float* __restrict__ x,
                    const float* __restrict__ conv_w,
                    const float* __restrict__ conv_b,
                    const float* __restrict__ fc1_w,
                    const float* __restrict__ fc1_b,
                    const float* __restrict__ fc2_w,
                    const float* __restrict__ fc2_b,
                    float* __restrict__ out)
{
    extern __shared__ float lds[];
    float4* hb  = (float4*)lds;              // [64 k4][64 img] float4
    float4* h2b = (float4*)(lds + LDS_H2);   // [16 k4][64 img] float4

    const int tid  = threadIdx.x;
    const int blk  = blockIdx.x;
    const long base_img = (long)blk * BLK_IMGS;

    const int w    = tid >> 6;       // wave 0..15
    const int lane = tid & 63;

    // ---- conv roles: wave = c*4 + imgHi (both uniform) ----
    //      lane = imgLo*4 + yh*2 + xh ; thread computes rows 4yh..4yh+3,
    //      cols 4xh..4xh+3 of channel c for image imgHi*16+imgLo.
    const int c     = __builtin_amdgcn_readfirstlane(w >> 2);   // 0..3
    const int imgHi = __builtin_amdgcn_readfirstlane(w & 3);    // 0..3
    const int imgLo = lane >> 2;     // 0..15
    const int yh    = (lane >> 1) & 1;
    const int xh    = lane & 1;
    const int img   = imgHi * 16 + imgLo;    // 0..63

    // conv taps: wave-uniform -> s_load -> SGPRs
    float ws[49];
    #pragma unroll
    for (int i = 0; i < 49; ++i) ws[i] = conv_w[c * 49 + i];
    const float cb = conv_b[c];

    // ---- conv: 16 input rows (12yh..12yh+15), 4 aligned float4 each ----
    float4 acc[4];
    #pragma unroll
    for (int yy = 0; yy < 4; ++yy) acc[yy] = make_float4(0.f, 0.f, 0.f, 0.f);

    const float* xi = x + (base_img + img) * 784 + yh * 12 * 28 + 12 * xh;
    #pragma unroll
    for (int rw = 0; rw < 16; ++rw) {
        const float* rp = xi + rw * 28;          // 16B aligned
        float4 r0 = *(const float4*)(rp + 0);
        float4 r1 = *(const float4*)(rp + 4);
        float4 r2 = *(const float4*)(rp + 8);
        float4 r3 = *(const float4*)(rp + 12);
        float r[16] = { r0.x, r0.y, r0.z, r0.w,
                        r1.x, r1.y, r1.z, r1.w,
                        r2.x, r2.y, r2.z, r2.w,
                        r3.x, r3.y, r3.z, r3.w };
        #pragma unroll
        for (int yy = 0; yy < 4; ++yy) {
            const int rr = rw - 3 * yy;          // tap row for output row yy
            if (rr >= 0 && rr <= 6) {
                #pragma unroll
                for (int kx = 0; kx < 7; ++kx) {
                    const float wv = ws[rr * 7 + kx];    // SGPR operand
                    acc[yy].x = fmaf(r[0 + kx], wv, acc[yy].x);
                    acc[yy].y = fmaf(r[3 + kx], wv, acc[yy].y);
                    acc[yy].z = fmaf(r[6 + kx], wv, acc[yy].z);
                    acc[yy].w = fmaf(r[9 + kx], wv, acc[yy].w);
                }
            }
        }
    }

    // bias + square -> hb (k-major: k4 = c*16 + y*2 + xh, img contiguous)
    #pragma unroll
    for (int yy = 0; yy < 4; ++yy) {
        float4 hv;
        hv.x = acc[yy].x + cb; hv.x *= hv.x;
        hv.y = acc[yy].y + cb; hv.y *= hv.y;
        hv.z = acc[yy].z + cb; hv.z *= hv.z;
        hv.w = acc[yy].w + cb; hv.w *= hv.w;
        const int k4 = c * 16 + (yh * 4 + yy) * 2 + xh;
        hb[k4 * 64 + img] = hv;
    }
    __syncthreads();   // hb complete

    // ---- fc1: wave w -> outputs 4w..4w+3, lanes = 64 images (v5 verbatim,
    //      pitch 64) ----
    {
        const int img64 = lane;
        const int w4    = __builtin_amdgcn_readfirstlane(w);
        const float* wbase = fc1_w + (w4 * 4) * 256;

        float a0 = 0.f, a1 = 0.f, a2 = 0.f, a3 = 0.f;

        #pragma unroll 4
        for (int k4 = 0; k4 < 64; ++k4) {
            float4 h4 = hb[k4 * 64 + img64];              // contiguous b128
            const float* wp = wbase + k4 * 4;
            float4 w0 = *(const float4*)(wp + 0 * 256);   // uniform -> s_load
            float4 w1 = *(const float4*)(wp + 1 * 256);
            float4 w2 = *(const float4*)(wp + 2 * 256);
            float4 w3 = *(const float4*)(wp + 3 * 256);
            a0 = fmaf(h4.x,w0.x,a0); a0 = fmaf(h4.y,w0.y,a0); a0 = fmaf(h4.z,w0.z,a0); a0 = fmaf(h4.w,w0.w,a0);
            a1 = fmaf(h4.x,w1.x,a1); a1 = fmaf(h4.y,w1.y,a1); a1 = fmaf(h4.z,w1.z,a1); a1 = fmaf(h4.w,w1.w,a1);
            a2 = fmaf(h4.x,w2.x,a2); a2 = fmaf(h4.y,w2.y,a2); a2 = fmaf(h4.z,w2.z,a2); a2 = fmaf(h4.w,w2.w,a2);
            a3 = fmaf(h4.x,w3.x,a3); a3 = fmaf(h4.y,w3.y,a3); a3 = fmaf(h4.z,w3.z,a3); a3 = fmaf(h4.w,w3.w,a3);
        }

        const float* bp = fc1_b + w4 * 4;   // uniform -> s_load
        float4 p0;
        p0.x = a0 + bp[0]; p0.x *= p0.x;
        p0.y = a1 + bp[1]; p0.y *= p0.y;
        p0.z = a2 + bp[2]; p0.z *= p0.z;
        p0.w = a3 + bp[3]; p0.w *= p0.w;
        h2b[w4 * 64 + img64] = p0;          // contiguous b128 write
    }
    __syncthreads();   // h2b complete

    // ---- fc2: wave j (0..9) -> output j for all 64 images ----
    if (w < 10) {
        const int j = __builtin_amdgcn_readfirstlane(w);
        float s = 0.f;
        #pragma unroll
        for (int k4 = 0; k4 < 16; ++k4) {
            float4 hh = h2b[k4 * 64 + lane];              // contiguous b128
            float4 wj = *(const float4*)(fc2_w + j * 64 + k4 * 4); // s_load
            s = fmaf(hh.x, wj.x, s); s = fmaf(hh.y, wj.y, s);
            s = fmaf(hh.z, wj.z, s); s = fmaf(hh.w, wj.w, s);
        }
        out[(long)blk * 640 + lane * 10 + j] = s + fc2_b[j];
    }
}

extern "C" void kernel_launch(void* const* d_in, const int* in_sizes, int n_in,
                              void* d_out, int out_size, void* d_ws, size_t ws_size,
                              hipStream_t stream) {
    const float* x      = (const float*)d_in[0];
    const float* conv_w = (const float*)d_in[1];
    const float* conv_b = (const float*)d_in[2];
    const float* fc1_w  = (const float*)d_in[3];
    const float* fc1_b  = (const float*)d_in[4];
    const float* fc2_w  = (const float*)d_in[5];
    const float* fc2_b  = (const float*)d_in[6];
    float* out = (float*)d_out;

    const int B = in_sizes[0] / 784;
    const int blocks = (B + BLK_IMGS - 1) / BLK_IMGS;      // 1024 for B=65536
    const size_t lds_bytes = LDS_TOTAL_F * sizeof(float);  // 81920 -> 2 blk/CU

    // dynamic LDS > 64KB needs the attribute raised (idempotent).
    static bool attr_set = false;
    if (!attr_set) {
        (void)hipFuncSetAttribute((const void*)encconv_fused7,
                                  hipFuncAttributeMaxDynamicSharedMemorySize,
                                  (int)lds_bytes);
        attr_set = true;
    }

    encconv_fused7<<<blocks, 1024, lds_bytes, stream>>>(
        x, conv_w, conv_b, fc1_w, fc1_b, fc2_w, fc2_b, out);
}

// Round 6
// 344.230 us; speedup vs baseline: 1.7827x; 1.2965x over previous
//
#include <hip/hip_runtime.h>

// EncConvNet fused v8: conv7x7s3+sq -> fc1+sq -> fc2, one kernel.
// v6/v7 both bundled regressions and never actually tested 2 blocks/CU
// (v7's 81920B x2 = exactly 160KiB failed co-residency; occupancy stayed 45%).
// v8 tests the hypothesis CLEANLY: BLK_IMGS=32, 512 threads, chunk=8,
// LDS 72704B (18KB slack under the 81920 threshold) -> genuine 2 blocks/CU.
// Independent per-block barriers let block A's conv (VALU-heavy) overlap
// block B's fc1 (LDS+SMEM-heavy) -- the phase decoupling v5's single
// lockstep block cannot get.
//  - conv: v5 verbatim (c wave-uniform -> 49 taps in SGPRs, zero spill at
//    the 64-VGPR budget; 7 rows x 4 b128 per thread; FMA order identical
//    -> bit-identical results). wave = c*2+ghi, lane = glo*16+y*2+xh.
//  - fc1: 8 waves x 8 outputs (v2-proven s_load of 8 weight quads/iter,
//    unroll 2). All lanes compute all 8 outputs (2x redundant VALU -- it
//    has headroom at 33%); lane keeps the half given by oh=lane>>5 via 8
//    one-time cndmasks. LDS reads per image unchanged from v5.
//  - fc2: v5 pattern at 512 threads: thread (im5=tid>>4, q=tid&15), q<10.
//  - hb pitch 33 float4: write bank (8y+4xh+4glo)%32 spread; fc1 read =
//    contiguous 512B x 2-lane broadcast (free).

#define BLK_IMGS    32
#define CHUNK_IMGS  8
#define NCHUNK      4
#define XCH_FLOATS  (CHUNK_IMGS * 784)   // 6272 floats per chunk
#define HB_PITCH    33                   // float4 pitch (32 imgs + 1 pad)
#define H2_PITCH    33

// LDS float offsets
#define LDS_XBUF    0                    // 6272 (single buffer)
#define LDS_H       6272                 // 64*33*4 = 8448 floats
#define LDS_H2      14720                // 16*33*4 = 2112 floats
#define LDS_W2      16832                // 1024 floats
#define LDS_OUT     17856                // 320 floats
#define LDS_TOTAL_F 18176                // -> 72704 bytes -> 2 blocks/CU

__global__ __launch_bounds__(512)
void encconv_fused8(const float* __restrict__ x,
                    const float* __restrict__ conv_w,
                    const float* __restrict__ conv_b,
                    const float* __restrict__ fc1_w,
                    const float* __restrict__ fc1_b,
                    const float* __restrict__ fc2_w,
                    const float* __restrict__ fc2_b,
                    float* __restrict__ out)
{
    extern __shared__ float lds[];
    float*  xbuf = lds + LDS_XBUF;
    float4* hb   = (float4*)(lds + LDS_H);
    float4* h2b  = (float4*)(lds + LDS_H2);
    float4* w2b  = (float4*)(lds + LDS_W2);
    float*  ob   = lds + LDS_OUT;

    const int tid  = threadIdx.x;
    const int blk  = blockIdx.x;
    const long base_img = (long)blk * BLK_IMGS;

    const int lane = tid & 63;
    const int wv   = tid >> 6;       // wave 0..7

    // ---- conv roles: wave = c*2 + ghi (both uniform) ----
    //      lane = glo*16 + y*2 + xh ; image g = ghi*4 + glo (0..7)
    const int c    = __builtin_amdgcn_readfirstlane(wv >> 1);   // 0..3
    const int ghi  = __builtin_amdgcn_readfirstlane(wv & 1);    // 0..1
    const int glo  = lane >> 4;      // 0..3
    const int y    = (lane >> 1) & 7;
    const int xh   = lane & 1;
    const int g    = ghi * 4 + glo;  // image-in-chunk 0..7

    // conv taps: wave-uniform address -> s_load -> SGPRs (zero VGPR cost)
    float ws[49];
    #pragma unroll
    for (int i = 0; i < 49; ++i) ws[i] = conv_w[c * 49 + i];
    const float cb = conv_b[c];

    // stage fc2_w into LDS, k-major: slot = kk*16 + j
    if (tid < 160) {
        float4 v = *(const float4*)(fc2_w + tid * 4);
        int e  = tid * 4;
        int j  = e >> 6;          // 0..9
        int kk = (e & 63) >> 2;   // 0..15
        w2b[kk * 16 + j] = v;
    }

    const float* xblk = x + base_img * 784;

    // ---- prefetch chunk 0 into registers (coalesced: 1568 float4) ----
    float4 pf0, pf1, pf2, pf3;
    {
        const float* src = xblk;
        pf0 = *(const float4*)(src + 4 * tid);
        pf1 = *(const float4*)(src + 4 * (tid + 512));
        pf2 = *(const float4*)(src + 4 * (tid + 1024));
        if (tid < 32) pf3 = *(const float4*)(src + 4 * (tid + 1536));
    }

    // ---- conv over 4 chunks of 8 images, single-buffered LDS ----
    for (int ch = 0; ch < NCHUNK; ++ch) {
        // commit prefetched regs to LDS (lane-contiguous ds_write_b128)
        *(float4*)(xbuf + 4 * tid)          = pf0;
        *(float4*)(xbuf + 4 * (tid + 512))  = pf1;
        *(float4*)(xbuf + 4 * (tid + 1024)) = pf2;
        if (tid < 32) *(float4*)(xbuf + 4 * (tid + 1536)) = pf3;
        __syncthreads();

        // issue next chunk's prefetch; conv compute below hides its latency
        if (ch + 1 < NCHUNK) {
            const float* src = xblk + (ch + 1) * XCH_FLOATS;
            pf0 = *(const float4*)(src + 4 * tid);
            pf1 = *(const float4*)(src + 4 * (tid + 512));
            pf2 = *(const float4*)(src + 4 * (tid + 1024));
            if (tid < 32) pf3 = *(const float4*)(src + 4 * (tid + 1536));
        }

        // conv: image g, row y, channel c (uniform), outputs 4xh..4xh+3
        float acc0 = 0.f, acc1 = 0.f, acc2 = 0.f, acc3 = 0.f;
        const float* xi = xbuf + g * 784;
        #pragma unroll
        for (int rr = 0; rr < 7; ++rr) {
            const float* rp = xi + (3 * y + rr) * 28 + 12 * xh;  // 16B aligned
            float4 r0 = *(const float4*)(rp + 0);
            float4 r1 = *(const float4*)(rp + 4);
            float4 r2 = *(const float4*)(rp + 8);
            float4 r3 = *(const float4*)(rp + 12);
            float r[16] = { r0.x, r0.y, r0.z, r0.w,
                            r1.x, r1.y, r1.z, r1.w,
                            r2.x, r2.y, r2.z, r2.w,
                            r3.x, r3.y, r3.z, r3.w };
            #pragma unroll
            for (int kx = 0; kx < 7; ++kx) {
                const float w = ws[rr * 7 + kx];     // SGPR operand
                acc0 = fmaf(r[0 + kx], w, acc0);
                acc1 = fmaf(r[3 + kx], w, acc1);
                acc2 = fmaf(r[6 + kx], w, acc2);
                acc3 = fmaf(r[9 + kx], w, acc3);
            }
        }

        // bias + square -> hb (k-major: k4 = c*16 + y*2 + xh)
        float4 hv;
        hv.x = acc0 + cb; hv.x *= hv.x;
        hv.y = acc1 + cb; hv.y *= hv.y;
        hv.z = acc2 + cb; hv.z *= hv.z;
        hv.w = acc3 + cb; hv.w *= hv.w;
        hb[(c * 16 + y * 2 + xh) * HB_PITCH + (ch * CHUNK_IMGS + g)] = hv;

        __syncthreads();   // hb chunk done; xbuf consumed (next commit safe)
    }

    // ---- fc1: wave -> outputs 8w..8w+7; lanes = 2 x 32 images ----
    {
        const int img = lane & 31;
        const int oh  = lane >> 5;                                 // 0 or 1
        const int w8  = __builtin_amdgcn_readfirstlane(wv);
        const float* wbase = fc1_w + (w8 * 8) * 256;

        float a0=0.f,a1=0.f,a2=0.f,a3=0.f,a4=0.f,a5=0.f,a6=0.f,a7=0.f;

        #pragma unroll 2
        for (int k4 = 0; k4 < 64; ++k4) {
            float4 h4 = hb[k4 * HB_PITCH + img];          // 512B + 2-lane bcast
            const float* wp = wbase + k4 * 4;
            float4 w0 = *(const float4*)(wp + 0 * 256);   // uniform -> s_load
            float4 w1 = *(const float4*)(wp + 1 * 256);
            float4 w2 = *(const float4*)(wp + 2 * 256);
            float4 w3 = *(const float4*)(wp + 3 * 256);
            float4 w4 = *(const float4*)(wp + 4 * 256);
            float4 w5 = *(const float4*)(wp + 5 * 256);
            float4 w6 = *(const float4*)(wp + 6 * 256);
            float4 w7 = *(const float4*)(wp + 7 * 256);
            a0 = fmaf(h4.x,w0.x,a0); a0 = fmaf(h4.y,w0.y,a0); a0 = fmaf(h4.z,w0.z,a0); a0 = fmaf(h4.w,w0.w,a0);
            a1 = fmaf(h4.x,w1.x,a1); a1 = fmaf(h4.y,w1.y,a1); a1 = fmaf(h4.z,w1.z,a1); a1 = fmaf(h4.w,w1.w,a1);
            a2 = fmaf(h4.x,w2.x,a2); a2 = fmaf(h4.y,w2.y,a2); a2 = fmaf(h4.z,w2.z,a2); a2 = fmaf(h4.w,w2.w,a2);
            a3 = fmaf(h4.x,w3.x,a3); a3 = fmaf(h4.y,w3.y,a3); a3 = fmaf(h4.z,w3.z,a3); a3 = fmaf(h4.w,w3.w,a3);
            a4 = fmaf(h4.x,w4.x,a4); a4 = fmaf(h4.y,w4.y,a4); a4 = fmaf(h4.z,w4.z,a4); a4 = fmaf(h4.w,w4.w,a4);
            a5 = fmaf(h4.x,w5.x,a5); a5 = fmaf(h4.y,w5.y,a5); a5 = fmaf(h4.z,w5.z,a5); a5 = fmaf(h4.w,w5.w,a5);
            a6 = fmaf(h4.x,w6.x,a6); a6 = fmaf(h4.y,w6.y,a6); a6 = fmaf(h4.z,w6.z,a6); a6 = fmaf(h4.w,w6.w,a6);
            a7 = fmaf(h4.x,w7.x,a7); a7 = fmaf(h4.y,w7.y,a7); a7 = fmaf(h4.z,w7.z,a7); a7 = fmaf(h4.w,w7.w,a7);
        }

        // lane keeps half oh: one-time select, then bias + square
        const float* bp = fc1_b + w8 * 8;   // uniform -> s_load
        float s0 = oh ? a4 : a0;  float b0 = oh ? bp[4] : bp[0];
        float s1 = oh ? a5 : a1;  float b1 = oh ? bp[5] : bp[1];
        float s2 = oh ? a6 : a2;  float b2 = oh ? bp[6] : bp[2];
        float s3 = oh ? a7 : a3;  float b3 = oh ? bp[7] : bp[3];
        float4 p0;
        p0.x = s0 + b0; p0.x *= p0.x;
        p0.y = s1 + b1; p0.y *= p0.y;
        p0.z = s2 + b2; p0.z *= p0.z;
        p0.w = s3 + b3; p0.w *= p0.w;
        h2b[(w8 * 2 + oh) * H2_PITCH + img] = p0;
    }
    __syncthreads();

    // ---- fc2: thread (im5 = tid>>4, q = tid&15), active q<10 ----
    {
        const int im5 = tid >> 4;     // 0..31
        const int q   = tid & 15;
        if (q < 10) {
            float s = 0.f;
            #pragma unroll
            for (int k4 = 0; k4 < 16; ++k4) {
                float4 hh = h2b[k4 * H2_PITCH + im5];
                float4 wA = w2b[k4 * 16 + q];
                s = fmaf(hh.x, wA.x, s); s = fmaf(hh.y, wA.y, s);
                s = fmaf(hh.z, wA.z, s); s = fmaf(hh.w, wA.w, s);
            }
            ob[im5 * 10 + q] = s + fc2_b[q];
        }
    }
    __syncthreads();

    // ---- coalesced output store: 320 floats per block ----
    if (tid < 80) {
        float4 v = *(const float4*)(ob + tid * 4);
        *(float4*)(out + (long)blk * 320 + tid * 4) = v;
    }
}

extern "C" void kernel_launch(void* const* d_in, const int* in_sizes, int n_in,
                              void* d_out, int out_size, void* d_ws, size_t ws_size,
                              hipStream_t stream) {
    const float* x      = (const float*)d_in[0];
    const float* conv_w = (const float*)d_in[1];
    const float* conv_b = (const float*)d_in[2];
    const float* fc1_w  = (const float*)d_in[3];
    const float* fc1_b  = (const float*)d_in[4];
    const float* fc2_w  = (const float*)d_in[5];
    const float* fc2_b  = (const float*)d_in[6];
    float* out = (float*)d_out;

    const int B = in_sizes[0] / 784;
    const int blocks = (B + BLK_IMGS - 1) / BLK_IMGS;      // 2048 for B=65536
    const size_t lds_bytes = LDS_TOTAL_F * sizeof(float);  // 72704 -> 2 blk/CU

    // dynamic LDS > 64KB needs the attribute raised (idempotent).
    static bool attr_set = false;
    if (!attr_set) {
        (void)hipFuncSetAttribute((const void*)encconv_fused8,
                                  hipFuncAttributeMaxDynamicSharedMemorySize,
                                  (int)lds_bytes);
        attr_set = true;
    }

    encconv_fused8<<<blocks, 512, lds_bytes, stream>>>(
        x, conv_w, conv_b, fc1_w, fc1_b, fc2_w, fc2_b, out);
}

// Round 7
// 334.232 us; speedup vs baseline: 1.8360x; 1.0299x over previous
//
#include <hip/hip_runtime.h>

// EncConvNet fused v9: conv7x7s3+sq -> fc1+sq -> fc2, one kernel.
// v2..v8 all ran at 16 waves/CU and all plateau at ~145us with every pipe
// <=45% -> latency-bound on wave count. v9 gets 24 waves/CU (3 blocks/CU):
// LDS = 50432 B via (a) conv chunk 8->4 images (xbuf 25->12.5 KB),
// (b) UNION of h2b+ob with the xbuf region (xbuf dead after last conv
// barrier; h2b/ob live only after), (c) w2b kept separate (always live).
//  - conv: all 512 threads active: thread = (c,g,y,xq) computes 2 output
//    cols (2xq,2xq+1). Row window = 10 floats at 6xq (even -> 8B aligned),
//    read as 5x ds_read_b64 with STATIC r[] indices (no lane-dynamic
//    indexing -> no scratch, the v7 mistake; no cndmask selects).
//    c wave-uniform -> 49 taps via s_load into SGPRs (spill-proof at the
//    64-VGPR budget). FMA order per output unchanged (rr asc, kx asc).
//  - hb pitch 33 float4: fc1 read side contiguous+broadcast, conflict-free;
//    conv b64 writes spread uniformly.
//  - fc1: v8 verbatim (8 waves x 8 outputs redundant-compute, s_load
//    weight quads, oh-select at end) - proven spill-free.
//  - fc2: v8 verbatim (im5 = tid>>4, q = tid&15<10, w2b k-major in LDS).

#define BLK_IMGS    32
#define CHUNK_IMGS  4
#define NCHUNK      8
#define XCH_FLOATS  (CHUNK_IMGS * 784)   // 3136 floats per chunk
#define HB_PITCH    33                   // float4 pitch (32 imgs + 1 pad)
#define H2_PITCH    33

// LDS float offsets
#define LDS_XBUF    0        // 3136 floats; UNION: h2b [0,2112), ob [2112,2432)
#define LDS_H       3136     // 64*33*4 = 8448 floats
#define LDS_W2      11584    // 1024 floats
#define LDS_TOTAL_F 12608    // 50432 bytes -> 3 blocks/CU (24 waves)

__global__ __launch_bounds__(512)
void encconv_fused9(const float* __restrict__ x,
                    const float* __restrict__ conv_w,
                    const float* __restrict__ conv_b,
                    const float* __restrict__ fc1_w,
                    const float* __restrict__ fc1_b,
                    const float* __restrict__ fc2_w,
                    const float* __restrict__ fc2_b,
                    float* __restrict__ out)
{
    extern __shared__ float lds[];
    float*  xbuf = lds + LDS_XBUF;
    float*  hbf  = lds + LDS_H;
    float4* hb   = (float4*)hbf;
    float4* h2b  = (float4*)(lds + LDS_XBUF);   // union: live after conv
    float*  ob   = lds + LDS_XBUF + 2112;       // union: live in fc2
    float4* w2b  = (float4*)(lds + LDS_W2);

    const int tid  = threadIdx.x;
    const int blk  = blockIdx.x;
    const long base_img = (long)blk * BLK_IMGS;

    const int lane = tid & 63;
    const int wv   = tid >> 6;       // wave 0..7

    // ---- conv roles: wave = c*2 + gh (both uniform) ----
    //      lane = gl*32 + y*4 + xq ; image g = gh*2 + gl (0..3)
    const int c    = __builtin_amdgcn_readfirstlane(wv >> 1);   // 0..3
    const int gh   = __builtin_amdgcn_readfirstlane(wv & 1);    // 0..1
    const int gl   = lane >> 5;      // 0..1
    const int y    = (lane >> 2) & 7;
    const int xq   = lane & 3;       // x-quarter: output cols 2xq, 2xq+1
    const int g    = gh * 2 + gl;    // image-in-chunk 0..3
    const int x0   = xq & 1;         // elem sub-slot in float4
    const int xh2  = xq >> 1;        // k4 x-half

    // conv taps: wave-uniform address -> s_load -> SGPRs (zero VGPR cost)
    float ws[49];
    #pragma unroll
    for (int i = 0; i < 49; ++i) ws[i] = conv_w[c * 49 + i];
    const float cb = conv_b[c];

    // stage fc2_w into LDS, k-major: slot = kk*16 + j  (w2b never clobbered)
    if (tid < 160) {
        float4 v = *(const float4*)(fc2_w + tid * 4);
        int e  = tid * 4;
        int j  = e >> 6;          // 0..9
        int kk = (e & 63) >> 2;   // 0..15
        w2b[kk * 16 + j] = v;
    }

    const float* xblk = x + base_img * 784;

    // ---- prefetch chunk 0 into registers (coalesced: 784 float4) ----
    float4 pf0, pf1;
    {
        pf0 = *(const float4*)(xblk + 4 * tid);
        if (tid < 272) pf1 = *(const float4*)(xblk + 4 * (tid + 512));
    }

    // ---- conv over 8 chunks of 4 images, single-buffered LDS ----
    for (int ch = 0; ch < NCHUNK; ++ch) {
        // commit prefetched regs to LDS (lane-contiguous ds_write_b128)
        *(float4*)(xbuf + 4 * tid) = pf0;
        if (tid < 272) *(float4*)(xbuf + 4 * (tid + 512)) = pf1;
        __syncthreads();

        // issue next chunk's prefetch; conv compute below hides its latency
        if (ch + 1 < NCHUNK) {
            const float* src = xblk + (ch + 1) * XCH_FLOATS;
            pf0 = *(const float4*)(src + 4 * tid);
            if (tid < 272) pf1 = *(const float4*)(src + 4 * (tid + 512));
        }

        // conv: image g, row y, channel c (uniform), output cols 2xq,2xq+1
        float acc0 = 0.f, acc1 = 0.f;
        const float* xi = xbuf + g * 784;
        #pragma unroll
        for (int rr = 0; rr < 7; ++rr) {
            // 10-float window at col 6xq (even -> 8B aligned): 5x b64,
            // all r[] indices STATIC (no lane-dynamic indexing -> no scratch)
            const float* rp = xi + (3 * y + rr) * 28 + 6 * xq;
            float2 q0 = *(const float2*)(rp + 0);
            float2 q1 = *(const float2*)(rp + 2);
            float2 q2 = *(const float2*)(rp + 4);
            float2 q3 = *(const float2*)(rp + 6);
            float2 q4 = *(const float2*)(rp + 8);
            float r[10] = { q0.x, q0.y, q1.x, q1.y, q2.x,
                            q2.y, q3.x, q3.y, q4.x, q4.y };
            #pragma unroll
            for (int kx = 0; kx < 7; ++kx) {
                const float w = ws[rr * 7 + kx];     // SGPR operand
                acc0 = fmaf(r[0 + kx], w, acc0);
                acc1 = fmaf(r[3 + kx], w, acc1);
            }
        }

        // bias + square -> hb (k-major: k4 = c*16 + y*2 + xh2, elems 2x0..+1)
        float h0 = acc0 + cb; h0 *= h0;
        float h1 = acc1 + cb; h1 *= h1;
        const int k4  = c * 16 + y * 2 + xh2;
        const int img = ch * CHUNK_IMGS + g;
        float2 hv2; hv2.x = h0; hv2.y = h1;
        *(float2*)(hbf + (k4 * HB_PITCH + img) * 4 + 2 * x0) = hv2;

        __syncthreads();   // hb chunk done; xbuf consumed (next commit safe)
    }
    // after this point xbuf is dead -> h2b/ob may reuse its region

    // ---- fc1: wave -> outputs 8w..8w+7; lanes = 2 x 32 images ----
    {
        const int img = lane & 31;
        const int oh  = lane >> 5;                                 // 0 or 1
        const int w8  = __builtin_amdgcn_readfirstlane(wv);
        const float* wbase = fc1_w + (w8 * 8) * 256;

        float a0=0.f,a1=0.f,a2=0.f,a3=0.f,a4=0.f,a5=0.f,a6=0.f,a7=0.f;

        #pragma unroll 2
        for (int k4 = 0; k4 < 64; ++k4) {
            float4 h4 = hb[k4 * HB_PITCH + img];          // 512B + 2-lane bcast
            const float* wp = wbase + k4 * 4;
            float4 w0 = *(const float4*)(wp + 0 * 256);   // uniform -> s_load
            float4 w1 = *(const float4*)(wp + 1 * 256);
            float4 w2 = *(const float4*)(wp + 2 * 256);
            float4 w3 = *(const float4*)(wp + 3 * 256);
            float4 w4 = *(const float4*)(wp + 4 * 256);
            float4 w5 = *(const float4*)(wp + 5 * 256);
            float4 w6 = *(const float4*)(wp + 6 * 256);
            float4 w7 = *(const float4*)(wp + 7 * 256);
            a0 = fmaf(h4.x,w0.x,a0); a0 = fmaf(h4.y,w0.y,a0); a0 = fmaf(h4.z,w0.z,a0); a0 = fmaf(h4.w,w0.w,a0);
            a1 = fmaf(h4.x,w1.x,a1); a1 = fmaf(h4.y,w1.y,a1); a1 = fmaf(h4.z,w1.z,a1); a1 = fmaf(h4.w,w1.w,a1);
            a2 = fmaf(h4.x,w2.x,a2); a2 = fmaf(h4.y,w2.y,a2); a2 = fmaf(h4.z,w2.z,a2); a2 = fmaf(h4.w,w2.w,a2);
            a3 = fmaf(h4.x,w3.x,a3); a3 = fmaf(h4.y,w3.y,a3); a3 = fmaf(h4.z,w3.z,a3); a3 = fmaf(h4.w,w3.w,a3);
            a4 = fmaf(h4.x,w4.x,a4); a4 = fmaf(h4.y,w4.y,a4); a4 = fmaf(h4.z,w4.z,a4); a4 = fmaf(h4.w,w4.w,a4);
            a5 = fmaf(h4.x,w5.x,a5); a5 = fmaf(h4.y,w5.y,a5); a5 = fmaf(h4.z,w5.z,a5); a5 = fmaf(h4.w,w5.w,a5);
            a6 = fmaf(h4.x,w6.x,a6); a6 = fmaf(h4.y,w6.y,a6); a6 = fmaf(h4.z,w6.z,a6); a6 = fmaf(h4.w,w6.w,a6);
            a7 = fmaf(h4.x,w7.x,a7); a7 = fmaf(h4.y,w7.y,a7); a7 = fmaf(h4.z,w7.z,a7); a7 = fmaf(h4.w,w7.w,a7);
        }

        // lane keeps half oh: one-time select, then bias + square
        const float* bp = fc1_b + w8 * 8;   // uniform -> s_load
        float s0 = oh ? a4 : a0;  float b0 = oh ? bp[4] : bp[0];
        float s1 = oh ? a5 : a1;  float b1 = oh ? bp[5] : bp[1];
        float s2 = oh ? a6 : a2;  float b2 = oh ? bp[6] : bp[2];
        float s3 = oh ? a7 : a3;  float b3 = oh ? bp[7] : bp[3];
        float4 p0;
        p0.x = s0 + b0; p0.x *= p0.x;
        p0.y = s1 + b1; p0.y *= p0.y;
        p0.z = s2 + b2; p0.z *= p0.z;
        p0.w = s3 + b3; p0.w *= p0.w;
        h2b[(w8 * 2 + oh) * H2_PITCH + img] = p0;
    }
    __syncthreads();

    // ---- fc2: thread (im5 = tid>>4, q = tid&15), active q<10 ----
    {
        const int im5 = tid >> 4;     // 0..31
        const int q   = tid & 15;
        if (q < 10) {
            float s = 0.f;
            #pragma unroll
            for (int k4 = 0; k4 < 16; ++k4) {
                float4 hh = h2b[k4 * H2_PITCH + im5];
                float4 wA = w2b[k4 * 16 + q];
                s = fmaf(hh.x, wA.x, s); s = fmaf(hh.y, wA.y, s);
                s = fmaf(hh.z, wA.z, s); s = fmaf(hh.w, wA.w, s);
            }
            ob[im5 * 10 + q] = s + fc2_b[q];
        }
    }
    __syncthreads();

    // ---- coalesced output store: 320 floats per block ----
    if (tid < 80) {
        float4 v = *(const float4*)(ob + tid * 4);
        *(float4*)(out + (long)blk * 320 + tid * 4) = v;
    }
}

extern "C" void kernel_launch(void* const* d_in, const int* in_sizes, int n_in,
                              void* d_out, int out_size, void* d_ws, size_t ws_size,
                              hipStream_t stream) {
    const float* x      = (const float*)d_in[0];
    const float* conv_w = (const float*)d_in[1];
    const float* conv_b = (const float*)d_in[2];
    const float* fc1_w  = (const float*)d_in[3];
    const float* fc1_b  = (const float*)d_in[4];
    const float* fc2_w  = (const float*)d_in[5];
    const float* fc2_b  = (const float*)d_in[6];
    float* out = (float*)d_out;

    const int B = in_sizes[0] / 784;
    const int blocks = (B + BLK_IMGS - 1) / BLK_IMGS;      // 2048 for B=65536
    const size_t lds_bytes = LDS_TOTAL_F * sizeof(float);  // 50432 B < 64KB

    encconv_fused9<<<blocks, 512, lds_bytes, stream>>>(
        x, conv_w, conv_b, fc1_w, fc1_b, fc2_w, fc2_b, out);
}